// Round 9
// baseline (65.753 us; speedup 1.0000x reference)
//
#include <hip/hip_runtime.h>
#include <hip/hip_bf16.h>
#include <stdint.h>

// Problem constants
#define D       256
#define KCB     1024
#define HW      1024        // 32*32
#define NROWS   32768       // 32*32*32
#define TOTAL   8388608     // 32*256*32*32

// ws layout (bytes)
#define WS_EMBBF 0          // 512 frags x 1KB = 524288 : bf16 codes, MFMA-B-frag order
#define WS_CINIT 524288     // 1024*4 : 1 - 0.5*|e|^2
#define WS_KEY   528384     // 32768*4 : final packed key per z-row
#define WS_PART  659456     // 512*4 : per-wave loss partials

typedef __bf16 bf16x8 __attribute__((ext_vector_type(8)));
typedef float  f32x4  __attribute__((ext_vector_type(4)));
typedef unsigned int u32x4 __attribute__((ext_vector_type(4)));

union Pack8 { __bf16 h[8]; bf16x8 v; u32x4 u; };
union FU    { float f; unsigned u; };

// ---------------- K1: frag-pack bf16 codes + c_init -------------------------
// Waves 0..511: frag f=(cb,kb): lane l holds emb[cb*16+(l&15)][kb*32+(l>>4)*8+j]
// (exact MFMA 16x16x32 B-frag layout, verified by R7/R8 passing kernels).
// Waves 512..1535: c_init[code] = 1 - 0.5*|e|^2.
__global__ __launch_bounds__(256) void k_prep(const float* __restrict__ emb,
                                              unsigned char* __restrict__ ws) {
  const int t = threadIdx.x;
  const int lane = t & 63;
  const int W = blockIdx.x * 4 + (t >> 6);   // 0..1535
  if (W < 512) {
    const int cb = W >> 3, kb = W & 7;
    const int code = cb * 16 + (lane & 15);
    const int d0   = kb * 32 + (lane >> 4) * 8;
    const float4 a = *reinterpret_cast<const float4*>(emb + code * D + d0);
    const float4 b = *reinterpret_cast<const float4*>(emb + code * D + d0 + 4);
    Pack8 p;
    p.h[0]=(__bf16)a.x; p.h[1]=(__bf16)a.y; p.h[2]=(__bf16)a.z; p.h[3]=(__bf16)a.w;
    p.h[4]=(__bf16)b.x; p.h[5]=(__bf16)b.y; p.h[6]=(__bf16)b.z; p.h[7]=(__bf16)b.w;
    *reinterpret_cast<u32x4*>(ws + WS_EMBBF + (size_t)(W * 64 + lane) * 16) = p.u;
  } else {
    const int code = W - 512;                // 0..1023
    const float4 v = *reinterpret_cast<const float4*>(emb + code * D + lane * 4);
    float ss = v.x * v.x + v.y * v.y + v.z * v.z + v.w * v.w;
    #pragma unroll
    for (int m = 1; m < 64; m <<= 1) ss += __shfl_xor(ss, m, 64);
    if (lane == 0)
      *reinterpret_cast<float*>(ws + WS_CINIT + code * 4) = 1.0f - 0.5f * ss;
  }
}

// ---------------- K2: streaming distances + argmin + loss -------------------
// 512 single-wave WGs. Wave = 64 z-rows stationary in regs (afrag[4][8], 128
// VGPR); stream all 1024 codes from L2 (frag-packed, 1 dwordx4/lane/frag).
// NO LDS, NO barriers, NO atomics. acc = 1 + z.e - 0.5|e|^2 (positive ->
// IEEE-bit monotone); key = (bits&~1023)|(1023-code); in-lane running max
// over 64 code-blocks, one 4-step shfl reduce at the end. Loss via identity
// sum_d(q-z)^2 = |z|^2 - 2(acc_w-1), zsq from f32 z in the prologue.
#define LOADF(S, CB) do {                                                     \
    const unsigned char* _e = embbf + (size_t)(CB) * 8192 + lane * 16;        \
    _Pragma("unroll")                                                         \
    for (int kb = 0; kb < 8; ++kb)                                            \
      S[kb] = *reinterpret_cast<const bf16x8*>(_e + kb * 1024);               \
  } while (0)

#define COMPUTE(S, CB) do {                                                   \
    const float ci = c_init[(CB) * 16 + crl];                                 \
    f32x4 a0 = {ci, ci, ci, ci}, a1 = {ci, ci, ci, ci};                       \
    f32x4 a2 = {ci, ci, ci, ci}, a3 = {ci, ci, ci, ci};                       \
    _Pragma("unroll")                                                         \
    for (int kb = 0; kb < 8; ++kb) {                                          \
      a0 = __builtin_amdgcn_mfma_f32_16x16x32_bf16(afrag[0][kb], S[kb], a0, 0, 0, 0); \
      a1 = __builtin_amdgcn_mfma_f32_16x16x32_bf16(afrag[1][kb], S[kb], a1, 0, 0, 0); \
      a2 = __builtin_amdgcn_mfma_f32_16x16x32_bf16(afrag[2][kb], S[kb], a2, 0, 0, 0); \
      a3 = __builtin_amdgcn_mfma_f32_16x16x32_bf16(afrag[3][kb], S[kb], a3, 0, 0, 0); \
    }                                                                         \
    const unsigned base = (unsigned)(1023 - (CB) * 16) - (unsigned)crl;       \
    _Pragma("unroll")                                                         \
    for (int r = 0; r < 4; ++r) {                                             \
      FU f0, f1, f2, f3;                                                      \
      f0.f = a0[r]; f1.f = a1[r]; f2.f = a2[r]; f3.f = a3[r];                 \
      const unsigned k0 = (f0.u & 0xFFFFFC00u) | base;                        \
      const unsigned k1 = (f1.u & 0xFFFFFC00u) | base;                        \
      const unsigned k2 = (f2.u & 0xFFFFFC00u) | base;                        \
      const unsigned k3 = (f3.u & 0xFFFFFC00u) | base;                        \
      kmax[0][r] = kmax[0][r] > k0 ? kmax[0][r] : k0;                         \
      kmax[1][r] = kmax[1][r] > k1 ? kmax[1][r] : k1;                         \
      kmax[2][r] = kmax[2][r] > k2 ? kmax[2][r] : k2;                         \
      kmax[3][r] = kmax[3][r] > k3 ? kmax[3][r] : k3;                         \
    }                                                                         \
  } while (0)

__global__ __launch_bounds__(64) void k_dist(const float* __restrict__ z,
                                             const unsigned char* __restrict__ embbf,
                                             const float* __restrict__ c_init,
                                             unsigned* __restrict__ key_out,
                                             float* __restrict__ partials) {
  const int lane = threadIdx.x;            // 0..63
  const int wid  = blockIdx.x;             // 0..511
  const int row0 = wid * 64;
  const int hw0  = row0 & 1023;
  const int crl  = lane & 15;
  const int g    = lane >> 4;              // 0..3
  const float* zb = z + (size_t)(row0 >> 10) * (D * HW) + hw0;

  // ---- Prologue: z -> A-frags (rows stationary) + per-row |z|^2
  bf16x8 afrag[4][8];
  float zsq[4];
  #pragma unroll
  for (int m = 0; m < 4; ++m) {
    float s2 = 0.f;
    #pragma unroll
    for (int kb = 0; kb < 8; ++kb) {
      Pack8 p;
      #pragma unroll
      for (int j = 0; j < 8; ++j) {
        const float f = zb[(size_t)(kb * 32 + g * 8 + j) * HW + m * 16 + crl];
        s2 += f * f;
        p.h[j] = (__bf16)f;
      }
      afrag[m][kb] = p.v;
    }
    zsq[m] = s2;
  }
  #pragma unroll
  for (int m = 0; m < 4; ++m) {            // full-row |z|^2 (sum over g-groups)
    zsq[m] += __shfl_xor(zsq[m], 16, 64);
    zsq[m] += __shfl_xor(zsq[m], 32, 64);
  }

  unsigned kmax[4][4];
  #pragma unroll
  for (int m = 0; m < 4; ++m)
    #pragma unroll
    for (int r = 0; r < 4; ++r) kmax[m][r] = 0u;

  // ---- Main loop: 64 code-blocks, 2-deep static prefetch, no barriers
  bf16x8 sA[8], sB[8];
  LOADF(sA, 0);
  for (int cb = 0; cb < 64; cb += 2) {
    LOADF(sB, cb + 1);
    COMPUTE(sA, cb);
    if (cb + 2 < 64) LOADF(sA, cb + 2);
    COMPUTE(sB, cb + 1);
  }

  // ---- Final argmax reduce over the 16 col-lanes (codes)
  #pragma unroll
  for (int s = 1; s <= 8; s <<= 1)
    #pragma unroll
    for (int m = 0; m < 4; ++m)
      #pragma unroll
      for (int r = 0; r < 4; ++r) {
        const unsigned o = __shfl_xor(kmax[m][r], s, 64);
        kmax[m][r] = kmax[m][r] > o ? kmax[m][r] : o;
      }

  // keys: rows m*16 + g*4 + r, written by lane crl==0 of each g-group
  if (crl == 0) {
    #pragma unroll
    for (int m = 0; m < 4; ++m)
      #pragma unroll
      for (int r = 0; r < 4; ++r)
        key_out[row0 + m * 16 + g * 4 + r] = kmax[m][r];
  }

  // loss: lane with crl == g*4+r holds zsq for row m*16+crl -> pair with key
  float myloss = 0.f;
  if ((crl >> 2) == g) {
    const int r = crl & 3;
    #pragma unroll
    for (int m = 0; m < 4; ++m) {
      FU fu; fu.u = kmax[m][r] & 0xFFFFFC00u;   // winner acc (trunc, positive)
      myloss += zsq[m] - 2.0f * (fu.f - 1.0f);
    }
  }
  #pragma unroll
  for (int s = 1; s < 64; s <<= 1) myloss += __shfl_xor(myloss, s, 64);
  if (lane == 0) partials[wid] = myloss;
}

// ---------------- K3: gather + transposed coalesced write -------------------
// 512 WGs x 256 thr, 64 rows each. R7-verified tail: coalesced 1KB row gather
// into XOR-swizzled LDS, b128 read + 4 coalesced scalar stores per dq.
__global__ __launch_bounds__(256) void k_combine(const unsigned* __restrict__ keys,
                                                 const float* __restrict__ embf32,
                                                 float* __restrict__ out) {
  __shared__ unsigned char gb[65536];
  __shared__ int idx_l[64];
  const int t = threadIdx.x;
  const int lane = t & 63;
  const int w = t >> 6;
  const int row0 = blockIdx.x * 64;
  const int b = row0 >> 10;
  const int hw0 = row0 & 1023;

  if (t < 64) idx_l[t] = 1023 - (int)(keys[row0 + t] & 1023u);
  __syncthreads();

  const float4* emb4 = reinterpret_cast<const float4*>(embf32);
  #pragma unroll
  for (int i = 0; i < 16; ++i) {
    const int r = w * 16 + i;
    const int k = idx_l[r];
    const float4 v = emb4[(size_t)k * 64 + lane];
    *reinterpret_cast<float4*>(
        &gb[r * 1024 + ((unsigned)(lane * 16) ^ (unsigned)((r & 7) << 4))]) = v;
  }
  __syncthreads();

  const int r = lane;
  const unsigned rsw = (unsigned)((r & 7) << 4);
  float* outb = out + (size_t)b * (D * HW) + (size_t)(hw0 + r);
  #pragma unroll
  for (int i = 0; i < 16; ++i) {
    const int dq = w * 16 + i;
    const f32x4 v = *reinterpret_cast<const f32x4*>(
        &gb[r * 1024 + ((unsigned)(dq * 16) ^ rsw)]);
    #pragma unroll
    for (int q = 0; q < 4; ++q)
      outb[(size_t)(dq * 4 + q) * HW] = v[q];
  }
}

// ---------------- K4: final loss reduce -------------------------------------
__global__ __launch_bounds__(256) void k_loss(const float* __restrict__ partials,
                                              float* __restrict__ out_loss) {
  const int t = threadIdx.x;
  float s = partials[t] + partials[t + 256];
  #pragma unroll
  for (int m = 1; m < 64; m <<= 1) s += __shfl_xor(s, m, 64);
  __shared__ float wsum[4];
  if ((t & 63) == 0) wsum[t >> 6] = s;
  __syncthreads();
  if (t == 0)
    out_loss[0] = 1.25f * (wsum[0] + wsum[1] + wsum[2] + wsum[3]) * (1.0f / 8388608.0f);
}

extern "C" void kernel_launch(void* const* d_in, const int* in_sizes, int n_in,
                              void* d_out, int out_size, void* d_ws, size_t ws_size,
                              hipStream_t stream) {
  (void)in_sizes; (void)n_in; (void)out_size; (void)ws_size;
  const float* z   = (const float*)d_in[0];
  const float* emb = (const float*)d_in[1];
  float* out = (float*)d_out;
  unsigned char* ws = (unsigned char*)d_ws;

  k_prep<<<384, 256, 0, stream>>>(emb, ws);
  k_dist<<<512, 64, 0, stream>>>(z, ws + WS_EMBBF,
                                 (const float*)(ws + WS_CINIT),
                                 (unsigned*)(ws + WS_KEY),
                                 (float*)(ws + WS_PART));
  k_combine<<<512, 256, 0, stream>>>((const unsigned*)(ws + WS_KEY), emb, out);
  k_loss<<<1, 256, 0, stream>>>((const float*)(ws + WS_PART), out + TOTAL);
}

// Round 10
// 41.832 us; speedup vs baseline: 1.5718x; 1.5718x over previous
//
#include <hip/hip_runtime.h>
#include <hip/hip_bf16.h>
#include <stdint.h>

// Problem constants
#define D       256
#define KCB     1024
#define HW      1024        // 32*32
#define NROWS   32768       // 32*32*32
#define TOTAL   8388608     // 32*256*32*32

// ws layout (bytes)
#define WS_EMBBF 0          // 512 frags x 1KB = 524288 : bf16 codes, MFMA-B-frag order
#define WS_CINIT 524288     // 1024*4 : 1 - 0.5*|e|^2

typedef __bf16 bf16x8 __attribute__((ext_vector_type(8)));
typedef float  f32x4  __attribute__((ext_vector_type(4)));
typedef unsigned int u32x4 __attribute__((ext_vector_type(4)));

union Pack8 { __bf16 h[8]; bf16x8 v; u32x4 u; };
union FU    { float f; unsigned u; };

// ---------------- K1: frag-pack bf16 codes + c_init + zero loss slot --------
// Waves 0..511: frag (cb,kb): lane l holds emb[cb*16+(l&15)][kb*32+(l>>4)*8+j]
// (exact MFMA 16x16x32 B-frag layout, R8/R9-verified).
__global__ __launch_bounds__(256) void k_prep(const float* __restrict__ emb,
                                              unsigned char* __restrict__ ws,
                                              float* __restrict__ loss_slot) {
  const int t = threadIdx.x;
  if (blockIdx.x == 0 && t == 0) *loss_slot = 0.0f;
  const int lane = t & 63;
  const int W = blockIdx.x * 4 + (t >> 6);   // 0..1535
  if (W < 512) {
    const int cb = W >> 3, kb = W & 7;
    const int code = cb * 16 + (lane & 15);
    const int d0   = kb * 32 + (lane >> 4) * 8;
    const float4 a = *reinterpret_cast<const float4*>(emb + code * D + d0);
    const float4 b = *reinterpret_cast<const float4*>(emb + code * D + d0 + 4);
    Pack8 p;
    p.h[0]=(__bf16)a.x; p.h[1]=(__bf16)a.y; p.h[2]=(__bf16)a.z; p.h[3]=(__bf16)a.w;
    p.h[4]=(__bf16)b.x; p.h[5]=(__bf16)b.y; p.h[6]=(__bf16)b.z; p.h[7]=(__bf16)b.w;
    *reinterpret_cast<u32x4*>(ws + WS_EMBBF + (size_t)(W * 64 + lane) * 16) = p.u;
  } else {
    const int code = W - 512;                // 0..1023
    const float4 v = *reinterpret_cast<const float4*>(emb + code * D + lane * 4);
    float ss = v.x * v.x + v.y * v.y + v.z * v.z + v.w * v.w;
    #pragma unroll
    for (int m = 1; m < 64; m <<= 1) ss += __shfl_xor(ss, m, 64);
    if (lane == 0)
      *reinterpret_cast<float*>(ws + WS_CINIT + code * 4) = 1.0f - 0.5f * ss;
  }
}

// ---------------- K2: fused dist+argmin+loss+gather+write -------------------
// 512 WGs x 256 thr (4 waves), 2 WG/CU (LDS ~66KB) -> 8 waves/CU.
// WG = 64 z-rows. z staged once to swizzled bf16 LDS; afrag[4][8] hoisted per
// wave (all waves, same 64 rows). Each wave streams a DISJOINT code-QUARTER
// (16 blocks) from L2 frag-packed -> NO barriers in main loop, no extra
// traffic (512 KB/WG total regardless of split). Final: LDS key combine,
// loss = |z|^2 - 2(acc_w-1), atomicAdd; then gather+transposed write (R8 tail).
#define LOADF(S, CB) do {                                                     \
    const unsigned char* _e = embbf + (size_t)(CB) * 8192 + lane * 16;        \
    _Pragma("unroll")                                                         \
    for (int kb = 0; kb < 8; ++kb)                                            \
      S[kb] = *reinterpret_cast<const bf16x8*>(_e + kb * 1024);               \
  } while (0)

#define COMPUTE(S, CB) do {                                                   \
    const float ci = c_init[(CB) * 16 + crl];                                 \
    f32x4 a0 = {ci, ci, ci, ci}, a1 = {ci, ci, ci, ci};                       \
    f32x4 a2 = {ci, ci, ci, ci}, a3 = {ci, ci, ci, ci};                       \
    _Pragma("unroll")                                                         \
    for (int kb = 0; kb < 8; ++kb) {                                          \
      a0 = __builtin_amdgcn_mfma_f32_16x16x32_bf16(afrag[0][kb], S[kb], a0, 0, 0, 0); \
      a1 = __builtin_amdgcn_mfma_f32_16x16x32_bf16(afrag[1][kb], S[kb], a1, 0, 0, 0); \
      a2 = __builtin_amdgcn_mfma_f32_16x16x32_bf16(afrag[2][kb], S[kb], a2, 0, 0, 0); \
      a3 = __builtin_amdgcn_mfma_f32_16x16x32_bf16(afrag[3][kb], S[kb], a3, 0, 0, 0); \
    }                                                                         \
    const unsigned base = (unsigned)(1023 - (CB) * 16) - (unsigned)crl;       \
    _Pragma("unroll")                                                         \
    for (int r = 0; r < 4; ++r) {                                             \
      FU f0, f1, f2, f3;                                                      \
      f0.f = a0[r]; f1.f = a1[r]; f2.f = a2[r]; f3.f = a3[r];                 \
      const unsigned k0 = (f0.u & 0xFFFFFC00u) | base;                        \
      const unsigned k1 = (f1.u & 0xFFFFFC00u) | base;                        \
      const unsigned k2 = (f2.u & 0xFFFFFC00u) | base;                        \
      const unsigned k3 = (f3.u & 0xFFFFFC00u) | base;                        \
      kmax[0][r] = kmax[0][r] > k0 ? kmax[0][r] : k0;                         \
      kmax[1][r] = kmax[1][r] > k1 ? kmax[1][r] : k1;                         \
      kmax[2][r] = kmax[2][r] > k2 ? kmax[2][r] : k2;                         \
      kmax[3][r] = kmax[3][r] > k3 ? kmax[3][r] : k3;                         \
    }                                                                         \
  } while (0)

__global__ __launch_bounds__(256, 2) void k_fused(const float* __restrict__ z,
                                                  const unsigned char* __restrict__ embbf,
                                                  const float* __restrict__ c_init,
                                                  const float* __restrict__ embf32,
                                                  float* __restrict__ out,
                                                  float* __restrict__ loss_slot) {
  __shared__ unsigned char smem[65536];  // [0,32K)=z_lds [32K,64K)=scratch/kbuf; later all = gb
  __shared__ float zsq_buf[4][64];
  __shared__ int   idx_l[64];

  unsigned char* z_lds = smem;
  float* scratch = reinterpret_cast<float*>(smem + 32768);

  const int t    = threadIdx.x;
  const int lane = t & 63;
  const int w    = t >> 6;        // 0..3 : code-quarter
  const int crl  = lane & 15;
  const int g    = lane >> 4;     // 0..3
  const int row0 = blockIdx.x * 64;
  const int b    = row0 >> 10;
  const int hw0  = row0 & 1023;
  const float* zb = z + (size_t)b * (D * HW) + hw0;

  // ---- Stage z: float4 global -> f32 scratch (128d x 64hw) -> bf16 swz LDS
  const int prow = t & 63;                 // pack row (hw)
  const int pq   = t >> 6;                 // pack quarter
  float zsq_part = 0.f;
  for (int c = 0; c < 2; ++c) {
    #pragma unroll
    for (int i = 0; i < 8; ++i) {
      const int idx = t + i * 256;         // 0..2047 float4-slots
      const int dl  = idx >> 4;            // 0..127
      const int hw4 = idx & 15;            // 0..15
      *reinterpret_cast<float4*>(scratch + dl * 64 + hw4 * 4) =
          *reinterpret_cast<const float4*>(zb + (size_t)(c * 128 + dl) * HW + hw4 * 4);
    }
    __syncthreads();
    #pragma unroll
    for (int kk = 0; kk < 4; ++kk) {
      const int kcI = pq + kk * 4;         // 0..15 (8 d each) within chunk
      Pack8 p;
      #pragma unroll
      for (int q = 0; q < 8; ++q) {
        const float f = scratch[(kcI * 8 + q) * 64 + prow];
        zsq_part += f * f;
        p.h[q] = (__bf16)f;
      }
      const unsigned u = (unsigned)(c * 256 + kcI * 16) ^ (unsigned)((prow & 7) << 4);
      *reinterpret_cast<u32x4*>(&z_lds[prow * 512 + u]) = p.u;
    }
    __syncthreads();
  }
  zsq_buf[pq][prow] = zsq_part;

  // ---- Hoist A-fragments: every wave loads all 64 rows x full K (128 VGPR)
  bf16x8 afrag[4][8];
  #pragma unroll
  for (int m = 0; m < 4; ++m) {
    const int rl = m * 16 + crl;
    const unsigned s = (unsigned)((rl & 7) << 4);
    #pragma unroll
    for (int kb = 0; kb < 8; ++kb) {
      const unsigned db = (unsigned)(kb * 64 + g * 16) ^ s;
      afrag[m][kb] = *reinterpret_cast<const bf16x8*>(&z_lds[rl * 512 + db]);
    }
  }

  unsigned kmax[4][4];
  #pragma unroll
  for (int m = 0; m < 4; ++m)
    #pragma unroll
    for (int r = 0; r < 4; ++r) kmax[m][r] = 0u;

  // ---- Main loop: 16 code-blocks (this wave's quarter), 2-deep prefetch,
  // NO barriers, NO LDS.
  {
    const int cb0 = w * 16;
    bf16x8 sA[8], sB[8];
    LOADF(sA, cb0);
    #pragma unroll
    for (int i = 0; i < 16; i += 2) {
      LOADF(sB, cb0 + i + 1);
      COMPUTE(sA, cb0 + i);
      if (i + 2 < 16) LOADF(sA, cb0 + i + 2);
      COMPUTE(sB, cb0 + i + 1);
    }
  }

  // ---- argmax reduce over the 16 col-lanes (codes within quarter)
  #pragma unroll
  for (int s = 1; s <= 8; s <<= 1)
    #pragma unroll
    for (int m = 0; m < 4; ++m)
      #pragma unroll
      for (int r = 0; r < 4; ++r) {
        const unsigned o = __shfl_xor(kmax[m][r], s, 64);
        kmax[m][r] = kmax[m][r] > o ? kmax[m][r] : o;
      }

  // combine the 4 quarter-waves per row (kbuf in dead scratch)
  unsigned* kbuf = reinterpret_cast<unsigned*>(smem + 32768);  // 64 x 4 u32
  if (crl == 0) {
    #pragma unroll
    for (int m = 0; m < 4; ++m)
      #pragma unroll
      for (int r = 0; r < 4; ++r)
        kbuf[(m * 16 + g * 4 + r) * 4 + w] = kmax[m][r];
  }
  __syncthreads();

  if (t < 64) {                             // wave 0 exactly
    const unsigned k0 = kbuf[t * 4 + 0], k1 = kbuf[t * 4 + 1];
    const unsigned k2 = kbuf[t * 4 + 2], k3 = kbuf[t * 4 + 3];
    unsigned km = k0 > k1 ? k0 : k1;
    const unsigned kn = k2 > k3 ? k2 : k3;
    km = km > kn ? km : kn;
    idx_l[t] = 1023 - (int)(km & 1023u);
    FU fu; fu.u = km & 0xFFFFFC00u;         // winner acc (trunc, positive)
    const float zsq = zsq_buf[0][t] + zsq_buf[1][t] + zsq_buf[2][t] + zsq_buf[3][t];
    float myloss = zsq - 2.0f * (fu.f - 1.0f);
    #pragma unroll
    for (int s = 1; s < 64; s <<= 1) myloss += __shfl_xor(myloss, s, 64);
    if (t == 0) atomicAdd(loss_slot, myloss * (1.25f / 8388608.0f));
  }
  __syncthreads();   // idx_l visible; kbuf read done -> smem reusable as gb

  // ---- Gather: 64 winner rows, coalesced 1KB each, swizzled LDS (gb=smem)
  const float4* emb4 = reinterpret_cast<const float4*>(embf32);
  #pragma unroll
  for (int i = 0; i < 16; ++i) {
    const int r = w * 16 + i;
    const int k = idx_l[r];
    const float4 v = emb4[(size_t)k * 64 + lane];
    *reinterpret_cast<float4*>(
        &smem[r * 1024 + ((unsigned)(lane * 16) ^ (unsigned)((r & 7) << 4))]) = v;
  }
  __syncthreads();

  // ---- Transposed write-out: lane = hw row; wave covers 64 d (16 dq);
  // b128 LDS read -> 4 coalesced scalar stores (256B/instr over hw).
  {
    const int r = lane;
    const unsigned rsw = (unsigned)((r & 7) << 4);
    float* outb = out + (size_t)b * (D * HW) + (size_t)(hw0 + r);
    #pragma unroll
    for (int i = 0; i < 16; ++i) {
      const int dq = w * 16 + i;
      const f32x4 v = *reinterpret_cast<const f32x4*>(
          &smem[r * 1024 + ((unsigned)(dq * 16) ^ rsw)]);
      #pragma unroll
      for (int q = 0; q < 4; ++q)
        outb[(size_t)(dq * 4 + q) * HW] = v[q];
    }
  }
}

extern "C" void kernel_launch(void* const* d_in, const int* in_sizes, int n_in,
                              void* d_out, int out_size, void* d_ws, size_t ws_size,
                              hipStream_t stream) {
  (void)in_sizes; (void)n_in; (void)out_size; (void)ws_size;
  const float* z   = (const float*)d_in[0];
  const float* emb = (const float*)d_in[1];
  float* out = (float*)d_out;
  unsigned char* ws = (unsigned char*)d_ws;

  k_prep<<<384, 256, 0, stream>>>(emb, ws, out + TOTAL);
  k_fused<<<512, 256, 0, stream>>>(z, ws + WS_EMBBF,
                                   (const float*)(ws + WS_CINIT),
                                   emb, out, out + TOTAL);
}